// Round 19
// baseline (265.511 us; speedup 1.0000x reference)
//
#include <hip/hip_runtime.h>
#include <stdint.h>

// Problem constants
#define BB    8
#define HH    16
#define SS    640
#define STOK  512
#define STMN  128
#define HD    64
#define DIM   1024
#define NEGINF (-1e18f)

typedef short v8s __attribute__((ext_vector_type(8)));
typedef float v4f __attribute__((ext_vector_type(4)));

static __device__ __forceinline__ ushort f2b(float f) {
    union { float f; uint32_t u; } x; x.f = f;
    uint32_t u = (x.u + 0x7FFFu + ((x.u >> 16) & 1u)) >> 16;
    return (ushort)u;
}
static __device__ __forceinline__ float b2f(ushort h) {
    union { uint32_t u; float f; } x; x.u = ((uint32_t)h) << 16;
    return x.f;
}

// async global->LDS, 16 B per lane; dest is wave-uniform base + lane*16
static __device__ __forceinline__ void gld16(const ushort* g, ushort* l) {
    __builtin_amdgcn_global_load_lds(
        (const __attribute__((address_space(1))) unsigned int*)g,
        (__attribute__((address_space(3))) unsigned int*)l, 16, 0, 0);
}

// ---------------------------------------------------------------------------
// Kernel A0: convert x and qkv_w to bf16; split out_w into bf16 hi/lo.
// ---------------------------------------------------------------------------
__global__ __launch_bounds__(256) void cvt_bf16(
    const float* __restrict__ stok, const float* __restrict__ stm,
    const float* __restrict__ W, const float* __restrict__ Wo,
    ushort* __restrict__ xb, ushort* __restrict__ Wb,
    ushort* __restrict__ Woh, ushort* __restrict__ Wol)
{
    const int i = blockIdx.x * 256 + threadIdx.x;
    const int XG = 5120 * 256;                      // float4-groups in x
    const int WG = 3072 * 256;                      // float4-groups in qkv_w
    if (i < XG + WG) {
        float4 v; ushort* dst;
        if (i < XG) {
            int row = i >> 8, g = i & 255;
            int b = row / SS, s = row % SS;
            const float* src = (s < STOK)
                ? stok + ((size_t)b * STOK + s) * DIM
                : stm  + ((size_t)b * STMN + (s - STOK)) * DIM;
            v = *reinterpret_cast<const float4*>(src + g * 4);
            dst = xb + (size_t)row * DIM + g * 4;
        } else {
            int j = i - XG;
            int row = j >> 8, g = j & 255;
            v = *reinterpret_cast<const float4*>(W + (size_t)row * DIM + g * 4);
            dst = Wb + (size_t)row * DIM + g * 4;
        }
        ushort4 o;
        o.x = f2b(v.x); o.y = f2b(v.y); o.z = f2b(v.z); o.w = f2b(v.w);
        *reinterpret_cast<ushort4*>(dst) = o;
    } else {
        int j = i - XG - WG;
        int row = j >> 8, g = j & 255;
        float4 v = *reinterpret_cast<const float4*>(Wo + (size_t)row * DIM + g * 4);
        ushort4 hi, lo;
        hi.x = f2b(v.x); lo.x = f2b(v.x - b2f(hi.x));
        hi.y = f2b(v.y); lo.y = f2b(v.y - b2f(hi.y));
        hi.z = f2b(v.z); lo.z = f2b(v.z - b2f(hi.z));
        hi.w = f2b(v.w); lo.w = f2b(v.w - b2f(hi.w));
        *reinterpret_cast<ushort4*>(&Woh[(size_t)row * DIM + g * 4]) = hi;
        *reinterpret_cast<ushort4*>(&Wol[(size_t)row * DIM + g * 4]) = lo;
    }
}

// ---------------------------------------------------------------------------
// Kernel A: QKV projection, LDS-staged MFMA GEMM (unchanged r13).
// ---------------------------------------------------------------------------
__global__ __launch_bounds__(256) void gemm_qkv_mfma(
    const ushort* __restrict__ xb, const ushort* __restrict__ Wb,
    const float* __restrict__ bias,
    ushort* __restrict__ qb, ushort* __restrict__ kb, ushort* __restrict__ vtb)
{
    __shared__ __align__(16) ushort As[64 * 32];     // 4 KB
    __shared__ __align__(16) ushort Bs[128 * 32];    // 8 KB
    const int t = threadIdx.x, lane = t & 63, w = t >> 6;
    const int swz = ((blockIdx.x & 7) * 240) + (blockIdx.x >> 3);
    const int nt = swz / 80, mt = swz % 80;
    const int mb = mt * 64, nb = nt * 128;
    const int wm = (w >> 1) * 32, wn = (w & 1) * 64;
    const int lg = lane >> 4, lc = lane & 15;

    const int ra = t >> 2, pa = t & 3;
    const ushort* gA = xb + (size_t)(mb + ra) * DIM + (pa ^ ((ra >> 1) & 3)) * 8;
    ushort* lA = As + (w * 64) * 8;
    const ushort* gB[2]; ushort* lB[2];
#pragma unroll
    for (int i = 0; i < 2; ++i) {
        int c = t + i * 256, rb = c >> 2, pb = c & 3;
        gB[i] = Wb + (size_t)(nb + rb) * DIM + (pb ^ ((rb >> 1) & 3)) * 8;
        lB[i] = Bs + (i * 256 + w * 64) * 8;
    }

    v4f acc[2][4];
#pragma unroll
    for (int i = 0; i < 2; ++i)
#pragma unroll
        for (int j = 0; j < 4; ++j) acc[i][j] = (v4f){0.f, 0.f, 0.f, 0.f};

    for (int kt = 0; kt < 32; ++kt) {
        const int ko = kt * 32;
        __syncthreads();
        gld16(gA + ko, lA);
        gld16(gB[0] + ko, lB[0]);
        gld16(gB[1] + ko, lB[1]);
        __syncthreads();
        v8s af[2], bf[4];
#pragma unroll
        for (int i = 0; i < 2; ++i) {
            int ar = wm + i * 16 + lc;
            af[i] = *reinterpret_cast<const v8s*>(&As[ar * 32 + (lg ^ ((ar >> 1) & 3)) * 8]);
        }
#pragma unroll
        for (int j = 0; j < 4; ++j) {
            int br = wn + j * 16 + lc;
            bf[j] = *reinterpret_cast<const v8s*>(&Bs[br * 32 + (lg ^ ((br >> 1) & 3)) * 8]);
        }
#pragma unroll
        for (int i = 0; i < 2; ++i)
#pragma unroll
            for (int j = 0; j < 4; ++j)
                acc[i][j] = __builtin_amdgcn_mfma_f32_16x16x32_bf16(af[i], bf[j], acc[i][j], 0, 0, 0);
    }

    const int nregion = nb >> 10;                  // 0=q 1=k 2=v
    if (nregion < 2) {
        ushort* dst = nregion ? kb : qb;
        const float scale = nregion ? 1.0f : 0.125f;
#pragma unroll
        for (int j = 0; j < 4; ++j) {
            int n = nb + wn + j * 16 + lc;
            int nn = n & 1023, h = nn >> 6, d = nn & 63;
            float bi = bias[n];
#pragma unroll
            for (int i = 0; i < 2; ++i) {
                int m0 = mb + wm + i * 16 + lg * 4;
                int b = m0 / SS, s0 = m0 % SS;
                size_t base = (((size_t)b * HH + h) * SS + s0) * HD + d;
#pragma unroll
                for (int r = 0; r < 4; ++r)
                    dst[base + (size_t)r * HD] = f2b((acc[i][j][r] + bi) * scale);
            }
        }
    } else {
#pragma unroll
        for (int j = 0; j < 4; ++j) {
            int n = nb + wn + j * 16 + lc;
            int nn = n & 1023, h = nn >> 6, d = nn & 63;
            float bi = bias[n];
#pragma unroll
            for (int i = 0; i < 2; ++i) {
                int m0 = mb + wm + i * 16 + lg * 4;   // 4 consecutive s, same b
                int b = m0 / SS, s0 = m0 % SS;
                ushort4 pk;
                pk.x = f2b(acc[i][j][0] + bi);
                pk.y = f2b(acc[i][j][1] + bi);
                pk.z = f2b(acc[i][j][2] + bi);
                pk.w = f2b(acc[i][j][3] + bi);
                *reinterpret_cast<ushort4*>(
                    &vtb[(((size_t)b * HH + h) * HD + d) * SS + s0]) = pk;
            }
        }
    }
}

// ---------------------------------------------------------------------------
// Kernel C: out projection, LDS-staged double-bf16 MFMA GEMM (unchanged r13).
// ---------------------------------------------------------------------------
__global__ __launch_bounds__(256) void gemm_out_mfma(
    const ushort* __restrict__ Xh, const ushort* __restrict__ Xl,
    const ushort* __restrict__ Wh, const ushort* __restrict__ Wl,
    const float* __restrict__ bias, float* __restrict__ out)
{
    __shared__ __align__(16) ushort Ah[64 * 32];
    __shared__ __align__(16) ushort Al[64 * 32];
    __shared__ __align__(16) ushort Bh[64 * 32];
    __shared__ __align__(16) ushort Bl[64 * 32];
    const int t = threadIdx.x, lane = t & 63, w = t >> 6;
    const int swz = ((blockIdx.x & 7) * 160) + (blockIdx.x >> 3);
    const int nt = swz / 80, mt = swz % 80;
    const int mb = mt * 64, nb = nt * 64;
    const int wm = (w >> 1) * 32, wn = (w & 1) * 32;
    const int lg = lane >> 4, lc = lane & 15;

    const int rr = t >> 2, pp = t & 3;
    const size_t goff = (size_t)rr * DIM + (pp ^ ((rr >> 1) & 3)) * 8;
    const ushort* gAh = Xh + (size_t)mb * DIM + goff;
    const ushort* gAl = Xl + (size_t)mb * DIM + goff;
    const ushort* gBh = Wh + (size_t)nb * DIM + goff;
    const ushort* gBl = Wl + (size_t)nb * DIM + goff;
    const int wchunk = (w * 64) * 8;

    v4f acc[2][2];
#pragma unroll
    for (int i = 0; i < 2; ++i)
#pragma unroll
        for (int j = 0; j < 2; ++j) acc[i][j] = (v4f){0.f, 0.f, 0.f, 0.f};

    for (int kt = 0; kt < 32; ++kt) {
        const int ko = kt * 32;
        __syncthreads();
        gld16(gAh + ko, Ah + wchunk);
        gld16(gAl + ko, Al + wchunk);
        gld16(gBh + ko, Bh + wchunk);
        gld16(gBl + ko, Bl + wchunk);
        __syncthreads();
        v8s ahf[2], alf[2], bhf[2], blf[2];
#pragma unroll
        for (int i = 0; i < 2; ++i) {
            int ar = wm + i * 16 + lc;
            int ao = ar * 32 + (lg ^ ((ar >> 1) & 3)) * 8;
            ahf[i] = *reinterpret_cast<const v8s*>(&Ah[ao]);
            alf[i] = *reinterpret_cast<const v8s*>(&Al[ao]);
            int br = wn + i * 16 + lc;
            int bo = br * 32 + (lg ^ ((br >> 1) & 3)) * 8;
            bhf[i] = *reinterpret_cast<const v8s*>(&Bh[bo]);
            blf[i] = *reinterpret_cast<const v8s*>(&Bl[bo]);
        }
#pragma unroll
        for (int i = 0; i < 2; ++i)
#pragma unroll
            for (int j = 0; j < 2; ++j)
                acc[i][j] = __builtin_amdgcn_mfma_f32_16x16x32_bf16(ahf[i], bhf[j], acc[i][j], 0, 0, 0);
#pragma unroll
        for (int i = 0; i < 2; ++i)
#pragma unroll
            for (int j = 0; j < 2; ++j)
                acc[i][j] = __builtin_amdgcn_mfma_f32_16x16x32_bf16(alf[i], bhf[j], acc[i][j], 0, 0, 0);
#pragma unroll
        for (int i = 0; i < 2; ++i)
#pragma unroll
            for (int j = 0; j < 2; ++j)
                acc[i][j] = __builtin_amdgcn_mfma_f32_16x16x32_bf16(ahf[i], blf[j], acc[i][j], 0, 0, 0);
    }

#pragma unroll
    for (int j = 0; j < 2; ++j) {
        int n = nb + wn + j * 16 + lc;
        float bi = bias[n];
#pragma unroll
        for (int i = 0; i < 2; ++i) {
            int m0 = mb + wm + i * 16 + lg * 4;
#pragma unroll
            for (int r = 0; r < 4; ++r)
                out[(size_t)(m0 + r) * DIM + n] = acc[i][j][r] + bi;
        }
    }
}

// ---------------------------------------------------------------------------
// Kernel B: single-pass attention, swapped QK^T, deferred normalization.
// r19: Amdahl fix — ALL serial sections parallelized across the 8 waves:
// qrel build split (rh, dt) 8-way; final phase split by dt (all 8 waves:
// overlay write -> barrier -> per-dt merge + rel-v MFMA + ctx write).
// Pfull widened to [32][664] so Rv (stride-72) + 4 f32 overlays fit in the
// dead region.  Sweep structure unchanged from r18 (4-way k-tile split).
// ---------------------------------------------------------------------------
__global__ __launch_bounds__(512) void attn_mfma(
    const ushort* __restrict__ qb, const ushort* __restrict__ kb,
    const ushort* __restrict__ vtb,
    const uint8_t* __restrict__ mtok, const uint8_t* __restrict__ mstm,
    const float* __restrict__ relk, const float* __restrict__ relv,
    const float* __restrict__ smk,  const float* __restrict__ smv,
    float* __restrict__ attn_out,
    ushort* __restrict__ ctxh, ushort* __restrict__ ctxl)
{
    __shared__ ushort qrel[32][72];
    __shared__ __align__(16) ushort Pfull[32][664];   // unnorm exp(score), bf16
    __shared__ ushort wbin[32][72];
    __shared__ float  linv[32];
    __shared__ float  ebuf[32];
    __shared__ float  pl[4][32], pe0[4][32], pe1[4][32];
    __shared__ uint64_t mlds[10];

    const int t    = threadIdx.x;
    const int lane = t & 63, w = t >> 6;            // 8 waves
    const int rh = w & 1, th = w >> 1;              // row-half, tile-quarter
    const int swz  = ((blockIdx.x & 7) * 320) + (blockIdx.x >> 3);  // XCD-contig
    const int qt = swz % 20, bh = swz / 20;
    const int b = bh >> 4, h = bh & 15;
    const int qbase = qt * 32;
    const bool qstm = (qt >= 16);
    const size_t bhoff = (size_t)bh * (SS * HD);
    const int wq = rh * 16, lg = lane >> 4, lc = lane & 15;
    const int RR = qstm ? 16 : 32;
    const int NV = qstm ? 33 : 65;
    const float* tabk = qstm ? smk : relk;

    // zero wbin cooperatively (u32 granularity, all 512 threads)
    {
        uint32_t* wb32 = reinterpret_cast<uint32_t*>(&wbin[0][0]);
        for (int i = t; i < 32 * 36; i += 512) wb32[i] = 0u;
    }

    // mask words: bit j of mlds[kt] covers key kt*64+j
    if (t < 10) {
        uint64_t m = 0;
        const int kb0 = t * 64;
#pragma unroll
        for (int j = 0; j < 64; ++j) {
            int kg = kb0 + j;
            uint8_t mb = (kg < STOK) ? mtok[b * STOK + kg] : mstm[b * STMN + kg - STOK];
            m |= ((uint64_t)(mb ? 1u : 0u)) << j;
        }
        mlds[t] = m;
    }

    // Q fragments (row = qbase+wq+lc): B-operand in swapped QK^T
    const int qrow = qbase + wq + lc;
    v8s aq0 = *reinterpret_cast<const v8s*>(&qb[bhoff + (size_t)qrow * HD + lg * 8]);
    v8s aq1 = *reinterpret_cast<const v8s*>(&qb[bhoff + (size_t)qrow * HD + 32 + lg * 8]);

    // qrel build split 8 ways: wave w handles (rh = w&1, dt = w>>1)
    {
        const int ndt = qstm ? 2 : 4;
        const int dtq = w >> 1;
        if (dtq < ndt) {
            const float* rp = tabk + (size_t)(dtq * 16 + lc) * HD;
            v8s bk0, bk1;
#pragma unroll
            for (int j = 0; j < 8; ++j) {
                bk0[j] = (short)f2b(rp[lg * 8 + j]);
                bk1[j] = (short)f2b(rp[32 + lg * 8 + j]);
            }
            v4f c4 = {0.f, 0.f, 0.f, 0.f};
            c4 = __builtin_amdgcn_mfma_f32_16x16x32_bf16(aq0, bk0, c4, 0, 0, 0);
            c4 = __builtin_amdgcn_mfma_f32_16x16x32_bf16(aq1, bk1, c4, 0, 0, 0);
#pragma unroll
            for (int r = 0; r < 4; ++r)
                qrel[wq + lg * 4 + r][dtq * 16 + lc] = f2b(c4[r]);
        }
        if (w < 2) {    // last column v = NV-1, scalar partial + shfl
            const float* rp = tabk + (size_t)(NV - 1) * HD;
            float part = 0.f;
#pragma unroll
            for (int j = 0; j < 8; ++j) {
                part += b2f((ushort)aq0[j]) * rp[lg * 8 + j];
                part += b2f((ushort)aq1[j]) * rp[32 + lg * 8 + j];
            }
            part += __shfl_xor(part, 16);
            part += __shfl_xor(part, 32);
            if (lg == 0) qrel[wq + lc][NV - 1] = f2b(part);
        }
    }
    __syncthreads();

    // per-lane scalars for this lane's single q-row
    const int gq = qbase + wq + lc;
    const float relLs = b2f(qrel[wq + lc][0]);
    const float relRs = b2f(qrel[wq + lc][2 * RR]);

    const int tile0 = qstm ? 8 : 0;
    const int ntiles = 10 - tile0;
    const int tstart = tile0 + (ntiles * th) / 4;
    const int tend   = tile0 + (ntiles * (th + 1)) / 4;

    float lsum1 = 0.f, e0 = 0.f, e1 = 0.f;
    v4f o[4];
#pragma unroll
    for (int dt = 0; dt < 4; ++dt) o[dt] = (v4f){0.f, 0.f, 0.f, 0.f};
    float* arow = attn_out + ((size_t)bh * SS + qbase) * SS;

    // ---- fused sweep over this wave's tile-quarter ----
    for (int kt = tstart; kt < tend; ++kt) {
        const ushort* kbase = kb + bhoff + (size_t)(kt * 64) * HD;
        const bool dorel = qstm || (kt < 8);
        const uint64_t mw = mlds[kt];
#pragma unroll
        for (int sub = 0; sub < 4; ++sub) {
            v8s bk0 = *reinterpret_cast<const v8s*>(&kbase[(sub * 16 + lc) * HD + lg * 8]);
            v8s bk1 = *reinterpret_cast<const v8s*>(&kbase[(sub * 16 + lc) * HD + 32 + lg * 8]);
            // SWAPPED: A = K-frag, B = Q-frag -> C[row=key][col=q]
            v4f c4 = {0.f, 0.f, 0.f, 0.f};
            c4 = __builtin_amdgcn_mfma_f32_16x16x32_bf16(bk0, aq0, c4, 0, 0, 0);
            c4 = __builtin_amdgcn_mfma_f32_16x16x32_bf16(bk1, aq1, c4, 0, 0, 0);
            const int kgb = kt * 64 + sub * 16 + lg * 4;   // lane's 4 consecutive keys
            float p4[4];
#pragma unroll
            for (int r = 0; r < 4; ++r) {
                int kg = kgb + r;
                int dlt = kg - gq;
                bool inband = dorel && (dlt > -RR) && (dlt < RR);
                float val = c4[r];
                if (dorel) {
                    float rv;
                    if (inband) rv = b2f(qrel[wq + lc][dlt + RR]);
                    else        rv = (dlt <= -RR) ? relLs : relRs;
                    val += rv;
                }
                if ((mw >> (sub * 16 + lg * 4 + r)) & 1) val = NEGINF;
                float p = __expf(val);              // UNNORMALIZED
                lsum1 += p;
                p4[r] = p;
                if (inband) wbin[wq + lc][dlt + RR] = f2b(p);
                else if (dorel) {
                    if (dlt <= -RR) e0 += p;
                    else            e1 += p;
                }
            }
            uint32_t lo = (uint32_t)f2b(p4[0]) | ((uint32_t)f2b(p4[1]) << 16);
            uint32_t hi = (uint32_t)f2b(p4[2]) | ((uint32_t)f2b(p4[3]) << 16);
            uint64_t pk64 = (uint64_t)lo | ((uint64_t)hi << 32);
            *reinterpret_cast<uint64_t*>(&Pfull[wq + lc][kgb]) = pk64;
        }
        // PV for this tile (A from own rows' Pfull, B = V^T frags)
        v8s ap0 = *reinterpret_cast<const v8s*>(&Pfull[wq + lc][kt * 64 + lg * 8]);
        v8s ap1 = *reinterpret_cast<const v8s*>(&Pfull[wq + lc][kt * 64 + 32 + lg * 8]);
        const ushort* vbase = vtb + bhoff + kt * 64;
#pragma unroll
        for (int dt = 0; dt < 4; ++dt) {
            v8s bv0 = *reinterpret_cast<const v8s*>(&vbase[(size_t)(dt * 16 + lc) * SS + lg * 8]);
            v8s bv1 = *reinterpret_cast<const v8s*>(&vbase[(size_t)(dt * 16 + lc) * SS + 32 + lg * 8]);
            o[dt] = __builtin_amdgcn_mfma_f32_16x16x32_bf16(ap0, bv0, o[dt], 0, 0, 0);
            o[dt] = __builtin_amdgcn_mfma_f32_16x16x32_bf16(ap1, bv1, o[dt], 0, 0, 0);
        }
    }

    // per-lane reduces over lg groups -> per-row partials for (rh, th)
    {
        float s = lsum1;
        s += __shfl_xor(s, 16); s += __shfl_xor(s, 32);
        float e0s = e0;
        e0s += __shfl_xor(e0s, 16); e0s += __shfl_xor(e0s, 32);
        float e1s = e1;
        e1s += __shfl_xor(e1s, 16); e1s += __shfl_xor(e1s, 32);
        if (lg == 0) {
            pl[th][wq + lc]  = s;
            pe0[th][wq + lc] = e0s;
            pe1[th][wq + lc] = e1s;
        }
    }
    __syncthreads();

    // combine quarters (one thread per row)
    if (t < 32) {
        int row = t;
        float ls  = pl[0][row] + pl[1][row] + pl[2][row] + pl[3][row];
        linv[row] = 1.f / ls;
        float e0s = pe0[0][row] + pe0[1][row] + pe0[2][row] + pe0[3][row];
        float e1s = pe1[0][row] + pe1[1][row] + pe1[2][row] + pe1[3][row];
        ebuf[row] = e1s;
        wbin[row][0] = f2b(e0s);
        if (qstm) wbin[row][32] = f2b(e1s);
    }
    __syncthreads();

    // ---- row-contiguous normalize+write of attn (nt stores); 4 rows/wave ----
    {
        int row = w * 4 + lg;
        float iv = linv[row];
        float* rowp = arow + (size_t)row * SS;
        if (qstm) {
            v4f z = (v4f){0.f, 0.f, 0.f, 0.f};
#pragma unroll
            for (int kt = 0; kt < 8; ++kt)
                __builtin_nontemporal_store(z,
                    reinterpret_cast<v4f*>(&rowp[kt * 64 + lc * 4]));
#pragma unroll
            for (int kt = 8; kt < 10; ++kt) {
                ushort4 pk = *reinterpret_cast<ushort4*>(&Pfull[row][kt * 64 + lc * 4]);
                v4f pv4;
                pv4[0] = b2f(pk.x) * iv;
                pv4[1] = b2f(pk.y) * iv;
                pv4[2] = b2f(pk.z) * iv;
                pv4[3] = b2f(pk.w) * iv;
                __builtin_nontemporal_store(pv4,
                    reinterpret_cast<v4f*>(&rowp[kt * 64 + lc * 4]));
            }
        } else {
#pragma unroll
            for (int kt = 0; kt < 10; ++kt) {
                ushort4 pk = *reinterpret_cast<ushort4*>(&Pfull[row][kt * 64 + lc * 4]);
                v4f pv4;
                pv4[0] = b2f(pk.x) * iv;
                pv4[1] = b2f(pk.y) * iv;
                pv4[2] = b2f(pk.z) * iv;
                pv4[3] = b2f(pk.w) * iv;
                __builtin_nontemporal_store(pv4,
                    reinterpret_cast<v4f*>(&rowp[kt * 64 + lc * 4]));
            }
        }
    }
    __syncthreads();

    // ---- overlay write (ALL waves) + rel-v staging ----
    // Pfull dead region layout (ushort idx): Rv 0..4607 (stride 72),
    // overlays (f32) at ushort idx 4608 + q*4096 (byte 9216 + q*8192).
    {
        float* ob = reinterpret_cast<float*>(&Pfull[0][0] + 4608) + th * 2048;
#pragma unroll
        for (int dt = 0; dt < 4; ++dt)
#pragma unroll
            for (int r = 0; r < 4; ++r)
                ob[(wq + lg * 4 + r) * 64 + dt * 16 + lc] = o[dt][r];
    }
    {
        ushort* Rv = &Pfull[0][0];
        const float* tabv = qstm ? smv : relv;
        for (int idx = t; idx < 64 * 64; idx += 512) {
            int d = idx >> 6, v = idx & 63;
            float f = (v < NV) ? tabv[(size_t)v * HD + d] : 0.f;
            Rv[d * 72 + v] = f2b(f);
        }
    }
    __syncthreads();

    // ---- final phase split by dt: wave (rh, th) handles dt = th ----
    {
        const int dtw = th;
        const float* obase = reinterpret_cast<const float*>(&Pfull[0][0] + 4608);
        v4f of = (v4f){0.f, 0.f, 0.f, 0.f};
#pragma unroll
        for (int q = 0; q < 4; ++q) {
            const float* ob = obase + q * 2048;
#pragma unroll
            for (int r = 0; r < 4; ++r)
                of[r] += ob[(wq + lg * 4 + r) * 64 + dtw * 16 + lc];
        }
        const ushort* Rv = &Pfull[0][0];
        v8s aw0 = *reinterpret_cast<const v8s*>(&wbin[wq + lc][lg * 8]);
        v8s aw1 = *reinterpret_cast<const v8s*>(&wbin[wq + lc][32 + lg * 8]);
        v8s bv0 = *reinterpret_cast<const v8s*>(&Rv[(dtw * 16 + lc) * 72 + lg * 8]);
        v8s bv1 = *reinterpret_cast<const v8s*>(&Rv[(dtw * 16 + lc) * 72 + 32 + lg * 8]);
        of = __builtin_amdgcn_mfma_f32_16x16x32_bf16(aw0, bv0, of, 0, 0, 0);
        of = __builtin_amdgcn_mfma_f32_16x16x32_bf16(aw1, bv1, of, 0, 0, 0);
        if (!qstm) {   // rank-1 fixup for bin v=64
#pragma unroll
            for (int r = 0; r < 4; ++r)
                of[r] += ebuf[wq + lg * 4 + r] * relv[(size_t)64 * HD + dtw * 16 + lc];
        }
        // normalize and write ctx as bf16 hi/lo [b][s][h*64+d]
#pragma unroll
        for (int r = 0; r < 4; ++r) {
            int gq2 = qbase + wq + lg * 4 + r;
            size_t idx = ((size_t)b * SS + gq2) * DIM + h * HD + dtw * 16 + lc;
            float v = of[r] * linv[wq + lg * 4 + r];
            ushort hi = f2b(v);
            ctxh[idx] = hi;
            ctxl[idx] = f2b(v - b2f(hi));
        }
    }
}

// ---------------------------------------------------------------------------
extern "C" void kernel_launch(void* const* d_in, const int* in_sizes, int n_in,
                              void* d_out, int out_size, void* d_ws, size_t ws_size,
                              hipStream_t stream)
{
    const float*   stok  = (const float*)d_in[0];
    const float*   stm   = (const float*)d_in[1];
    const uint8_t* mtok  = (const uint8_t*)d_in[2];
    const uint8_t* mstm  = (const uint8_t*)d_in[3];
    const float*   qkv_w = (const float*)d_in[4];
    const float*   qkv_b = (const float*)d_in[5];
    const float*   out_w = (const float*)d_in[6];
    const float*   out_b = (const float*)d_in[7];
    const float*   relk  = (const float*)d_in[8];
    const float*   relv  = (const float*)d_in[9];
    const float*   smk   = (const float*)d_in[10];
    const float*   smv   = (const float*)d_in[11];

    float* out_final = (float*)d_out;
    float* out_attn  = out_final + (size_t)BB * SS * DIM;

    const size_t SZ = (size_t)BB * HH * SS * HD;           // 5,242,880
    ushort* qb16 = (ushort*)d_ws;
    ushort* kb16 = qb16 + SZ;
    ushort* vt16 = kb16 + SZ;
    ushort* xb16 = vt16 + SZ;                              // 5,242,880 ushorts
    ushort* wb16 = xb16 + SZ;                              // 3,145,728 ushorts
    ushort* ctxh = wb16 + (size_t)3 * DIM * DIM;
    ushort* ctxl = ctxh + SZ;
    ushort* woh  = ctxl + SZ;                              // 1,048,576 ushorts
    ushort* wol  = woh + (size_t)DIM * DIM;

    cvt_bf16<<<dim3(9216), dim3(256), 0, stream>>>(stok, stm, qkv_w, out_w,
                                                   xb16, wb16, woh, wol);
    gemm_qkv_mfma<<<dim3(1920), dim3(256), 0, stream>>>(xb16, wb16, qkv_b, qb16, kb16, vt16);
    attn_mfma<<<dim3(2560), dim3(512), 0, stream>>>(qb16, kb16, vt16, mtok, mstm,
                                                    relk, relv, smk, smv, out_attn, ctxh, ctxl);
    gemm_out_mfma<<<dim3(1280), dim3(256), 0, stream>>>(ctxh, ctxl, woh, wol, out_b, out_final);
}

// Round 21
// 241.855 us; speedup vs baseline: 1.0978x; 1.0978x over previous
//
#include <hip/hip_runtime.h>
#include <stdint.h>

// Problem constants
#define BB    8
#define HH    16
#define SS    640
#define STOK  512
#define STMN  128
#define HD    64
#define DIM   1024
#define NEGINF (-1e18f)

typedef short v8s __attribute__((ext_vector_type(8)));
typedef float v4f __attribute__((ext_vector_type(4)));

static __device__ __forceinline__ ushort f2b(float f) {
    union { float f; uint32_t u; } x; x.f = f;
    uint32_t u = (x.u + 0x7FFFu + ((x.u >> 16) & 1u)) >> 16;
    return (ushort)u;
}
static __device__ __forceinline__ float b2f(ushort h) {
    union { uint32_t u; float f; } x; x.u = ((uint32_t)h) << 16;
    return x.f;
}

// async global->LDS, 16 B per lane; dest is wave-uniform base + lane*16
static __device__ __forceinline__ void gld16(const ushort* g, ushort* l) {
    __builtin_amdgcn_global_load_lds(
        (const __attribute__((address_space(1))) unsigned int*)g,
        (__attribute__((address_space(3))) unsigned int*)l, 16, 0, 0);
}

// ---------------------------------------------------------------------------
// Kernel A0: convert x and qkv_w to bf16; split out_w into bf16 hi/lo.
// ---------------------------------------------------------------------------
__global__ __launch_bounds__(256) void cvt_bf16(
    const float* __restrict__ stok, const float* __restrict__ stm,
    const float* __restrict__ W, const float* __restrict__ Wo,
    ushort* __restrict__ xb, ushort* __restrict__ Wb,
    ushort* __restrict__ Woh, ushort* __restrict__ Wol)
{
    const int i = blockIdx.x * 256 + threadIdx.x;
    const int XG = 5120 * 256;                      // float4-groups in x
    const int WG = 3072 * 256;                      // float4-groups in qkv_w
    if (i < XG + WG) {
        float4 v; ushort* dst;
        if (i < XG) {
            int row = i >> 8, g = i & 255;
            int b = row / SS, s = row % SS;
            const float* src = (s < STOK)
                ? stok + ((size_t)b * STOK + s) * DIM
                : stm  + ((size_t)b * STMN + (s - STOK)) * DIM;
            v = *reinterpret_cast<const float4*>(src + g * 4);
            dst = xb + (size_t)row * DIM + g * 4;
        } else {
            int j = i - XG;
            int row = j >> 8, g = j & 255;
            v = *reinterpret_cast<const float4*>(W + (size_t)row * DIM + g * 4);
            dst = Wb + (size_t)row * DIM + g * 4;
        }
        ushort4 o;
        o.x = f2b(v.x); o.y = f2b(v.y); o.z = f2b(v.z); o.w = f2b(v.w);
        *reinterpret_cast<ushort4*>(dst) = o;
    } else {
        int j = i - XG - WG;
        int row = j >> 8, g = j & 255;
        float4 v = *reinterpret_cast<const float4*>(Wo + (size_t)row * DIM + g * 4);
        ushort4 hi, lo;
        hi.x = f2b(v.x); lo.x = f2b(v.x - b2f(hi.x));
        hi.y = f2b(v.y); lo.y = f2b(v.y - b2f(hi.y));
        hi.z = f2b(v.z); lo.z = f2b(v.z - b2f(hi.z));
        hi.w = f2b(v.w); lo.w = f2b(v.w - b2f(hi.w));
        *reinterpret_cast<ushort4*>(&Woh[(size_t)row * DIM + g * 4]) = hi;
        *reinterpret_cast<ushort4*>(&Wol[(size_t)row * DIM + g * 4]) = lo;
    }
}

// ---------------------------------------------------------------------------
// Kernel A: QKV projection, m97-geometry LDS-staged MFMA GEMM.
// 128x128 tile, BK=32 (960 blocks); 4 waves (2x2), wave 64x64 = 4x4 frags,
// 16 MFMA/wave/step; 16 KB staged/step.  nt-major XCD swizzle.
// ---------------------------------------------------------------------------
__global__ __launch_bounds__(256) void gemm_qkv_mfma(
    const ushort* __restrict__ xb, const ushort* __restrict__ Wb,
    const float* __restrict__ bias,
    ushort* __restrict__ qb, ushort* __restrict__ kb, ushort* __restrict__ vtb)
{
    __shared__ __align__(16) ushort As[128 * 32];    // 8 KB
    __shared__ __align__(16) ushort Bs[128 * 32];    // 8 KB
    const int t = threadIdx.x, lane = t & 63, w = t >> 6;
    const int swz = ((blockIdx.x & 7) * 120) + (blockIdx.x >> 3);
    const int nt = swz / 40, mt = swz % 40;
    const int mb = mt * 128, nb = nt * 128;
    const int wm = (w >> 1) * 64, wn = (w & 1) * 64;
    const int lg = lane >> 4, lc = lane & 15;

    // staging: A 512 chunks + B 512 chunks; thread t: A{t,t+256}, B{t,t+256}
    const ushort* gA[2]; ushort* lA[2];
    const ushort* gB[2]; ushort* lB[2];
#pragma unroll
    for (int i = 0; i < 2; ++i) {
        int c = t + i * 256, r = c >> 2, p = c & 3;
        gA[i] = xb + (size_t)(mb + r) * DIM + (p ^ ((r >> 1) & 3)) * 8;
        lA[i] = As + (i * 256 + w * 64) * 8;
        gB[i] = Wb + (size_t)(nb + r) * DIM + (p ^ ((r >> 1) & 3)) * 8;
        lB[i] = Bs + (i * 256 + w * 64) * 8;
    }

    v4f acc[4][4];
#pragma unroll
    for (int i = 0; i < 4; ++i)
#pragma unroll
        for (int j = 0; j < 4; ++j) acc[i][j] = (v4f){0.f, 0.f, 0.f, 0.f};

    for (int kt = 0; kt < 32; ++kt) {
        const int ko = kt * 32;
        __syncthreads();
        gld16(gA[0] + ko, lA[0]);
        gld16(gA[1] + ko, lA[1]);
        gld16(gB[0] + ko, lB[0]);
        gld16(gB[1] + ko, lB[1]);
        __syncthreads();
        v8s af[4], bf[4];
#pragma unroll
        for (int i = 0; i < 4; ++i) {
            int ar = wm + i * 16 + lc;
            af[i] = *reinterpret_cast<const v8s*>(&As[ar * 32 + (lg ^ ((ar >> 1) & 3)) * 8]);
            int br = wn + i * 16 + lc;
            bf[i] = *reinterpret_cast<const v8s*>(&Bs[br * 32 + (lg ^ ((br >> 1) & 3)) * 8]);
        }
#pragma unroll
        for (int i = 0; i < 4; ++i)
#pragma unroll
            for (int j = 0; j < 4; ++j)
                acc[i][j] = __builtin_amdgcn_mfma_f32_16x16x32_bf16(af[i], bf[j], acc[i][j], 0, 0, 0);
    }

    const int nregion = nb >> 10;                  // 0=q 1=k 2=v
    if (nregion < 2) {
        ushort* dst = nregion ? kb : qb;
        const float scale = nregion ? 1.0f : 0.125f;
#pragma unroll
        for (int j = 0; j < 4; ++j) {
            int n = nb + wn + j * 16 + lc;
            int nn = n & 1023, h = nn >> 6, d = nn & 63;
            float bi = bias[n];
#pragma unroll
            for (int i = 0; i < 4; ++i) {
                int m0 = mb + wm + i * 16 + lg * 4;
                int b = m0 / SS, s0 = m0 % SS;
                size_t base = (((size_t)b * HH + h) * SS + s0) * HD + d;
#pragma unroll
                for (int r = 0; r < 4; ++r)
                    dst[base + (size_t)r * HD] = f2b((acc[i][j][r] + bi) * scale);
            }
        }
    } else {
#pragma unroll
        for (int j = 0; j < 4; ++j) {
            int n = nb + wn + j * 16 + lc;
            int nn = n & 1023, h = nn >> 6, d = nn & 63;
            float bi = bias[n];
#pragma unroll
            for (int i = 0; i < 4; ++i) {
                int m0 = mb + wm + i * 16 + lg * 4;   // 4 consecutive s, same b
                int b = m0 / SS, s0 = m0 % SS;
                ushort4 pk;
                pk.x = f2b(acc[i][j][0] + bi);
                pk.y = f2b(acc[i][j][1] + bi);
                pk.z = f2b(acc[i][j][2] + bi);
                pk.w = f2b(acc[i][j][3] + bi);
                *reinterpret_cast<ushort4*>(
                    &vtb[(((size_t)b * HH + h) * HD + d) * SS + s0]) = pk;
            }
        }
    }
}

// ---------------------------------------------------------------------------
// Kernel C: out projection, LDS-staged double-bf16 MFMA GEMM.
// 64x128 tile (640 blocks, m-major XCD swizzle).  Wave 32x64 = 2x4 frags,
// fused hi/lo passes = 24 MFMA/step; 24 KB staged.
// ---------------------------------------------------------------------------
__global__ __launch_bounds__(256) void gemm_out_mfma(
    const ushort* __restrict__ Xh, const ushort* __restrict__ Xl,
    const ushort* __restrict__ Wh, const ushort* __restrict__ Wl,
    const float* __restrict__ bias, float* __restrict__ out)
{
    __shared__ __align__(16) ushort Ah[64 * 32];     // 4 KB
    __shared__ __align__(16) ushort Al[64 * 32];     // 4 KB
    __shared__ __align__(16) ushort Bh[128 * 32];    // 8 KB
    __shared__ __align__(16) ushort Bl[128 * 32];    // 8 KB
    const int t = threadIdx.x, lane = t & 63, w = t >> 6;
    // m-major: XCD k owns swz in [80k,80k+80) -> mt in [10k,10k+10), all nt
    const int swz = ((blockIdx.x & 7) * 80) + (blockIdx.x >> 3);
    const int mt = swz >> 3, nt = swz & 7;
    const int mb = mt * 64, nb = nt * 128;
    const int wm = (w >> 1) * 32, wn = (w & 1) * 64;
    const int lg = lane >> 4, lc = lane & 15;

    // staging: A hi/lo 256 chunks each (1/thread), B hi/lo 512 each (2/thread)
    const int ra = t >> 2, pa = t & 3;
    const size_t goffA = (size_t)ra * DIM + (pa ^ ((ra >> 1) & 3)) * 8;
    const ushort* gAh = Xh + (size_t)mb * DIM + goffA;
    const ushort* gAl = Xl + (size_t)mb * DIM + goffA;
    ushort* lAh = Ah + (w * 64) * 8;
    ushort* lAl = Al + (w * 64) * 8;
    const ushort* gBh[2]; const ushort* gBl[2]; ushort* lBh[2]; ushort* lBl[2];
#pragma unroll
    for (int i = 0; i < 2; ++i) {
        int c = t + i * 256, r = c >> 2, p = c & 3;
        size_t go = (size_t)(nb + r) * DIM + (p ^ ((r >> 1) & 3)) * 8;
        gBh[i] = Wh + go;
        gBl[i] = Wl + go;
        lBh[i] = Bh + (i * 256 + w * 64) * 8;
        lBl[i] = Bl + (i * 256 + w * 64) * 8;
    }

    v4f acc[2][4];
#pragma unroll
    for (int i = 0; i < 2; ++i)
#pragma unroll
        for (int j = 0; j < 4; ++j) acc[i][j] = (v4f){0.f, 0.f, 0.f, 0.f};

    for (int kt = 0; kt < 32; ++kt) {
        const int ko = kt * 32;
        __syncthreads();
        gld16(gAh + ko, lAh);
        gld16(gAl + ko, lAl);
        gld16(gBh[0] + ko, lBh[0]);
        gld16(gBh[1] + ko, lBh[1]);
        gld16(gBl[0] + ko, lBl[0]);
        gld16(gBl[1] + ko, lBl[1]);
        __syncthreads();
        v8s ahf[2], alf[2], bhf[4], blf[4];
#pragma unroll
        for (int i = 0; i < 2; ++i) {
            int ar = wm + i * 16 + lc;
            int ao = ar * 32 + (lg ^ ((ar >> 1) & 3)) * 8;
            ahf[i] = *reinterpret_cast<const v8s*>(&Ah[ao]);
            alf[i] = *reinterpret_cast<const v8s*>(&Al[ao]);
        }
#pragma unroll
        for (int j = 0; j < 4; ++j) {
            int br = wn + j * 16 + lc;
            int bo = br * 32 + (lg ^ ((br >> 1) & 3)) * 8;
            bhf[j] = *reinterpret_cast<const v8s*>(&Bh[bo]);
            blf[j] = *reinterpret_cast<const v8s*>(&Bl[bo]);
        }
#pragma unroll
        for (int i = 0; i < 2; ++i)
#pragma unroll
            for (int j = 0; j < 4; ++j)
                acc[i][j] = __builtin_amdgcn_mfma_f32_16x16x32_bf16(ahf[i], bhf[j], acc[i][j], 0, 0, 0);
#pragma unroll
        for (int i = 0; i < 2; ++i)
#pragma unroll
            for (int j = 0; j < 4; ++j)
                acc[i][j] = __builtin_amdgcn_mfma_f32_16x16x32_bf16(alf[i], bhf[j], acc[i][j], 0, 0, 0);
#pragma unroll
        for (int i = 0; i < 2; ++i)
#pragma unroll
            for (int j = 0; j < 4; ++j)
                acc[i][j] = __builtin_amdgcn_mfma_f32_16x16x32_bf16(ahf[i], blf[j], acc[i][j], 0, 0, 0);
    }

#pragma unroll
    for (int j = 0; j < 4; ++j) {
        int n = nb + wn + j * 16 + lc;
        float bi = bias[n];
#pragma unroll
        for (int i = 0; i < 2; ++i) {
            int m0 = mb + wm + i * 16 + lg * 4;
#pragma unroll
            for (int r = 0; r < 4; ++r)
                out[(size_t)(m0 + r) * DIM + n] = acc[i][j][r] + bi;
        }
    }
}

// ---------------------------------------------------------------------------
// Kernel B: single-pass attention (r19, unchanged — declared floored ~145us).
// ---------------------------------------------------------------------------
__global__ __launch_bounds__(512) void attn_mfma(
    const ushort* __restrict__ qb, const ushort* __restrict__ kb,
    const ushort* __restrict__ vtb,
    const uint8_t* __restrict__ mtok, const uint8_t* __restrict__ mstm,
    const float* __restrict__ relk, const float* __restrict__ relv,
    const float* __restrict__ smk,  const float* __restrict__ smv,
    float* __restrict__ attn_out,
    ushort* __restrict__ ctxh, ushort* __restrict__ ctxl)
{
    __shared__ ushort qrel[32][72];
    __shared__ __align__(16) ushort Pfull[32][664];   // unnorm exp(score), bf16
    __shared__ ushort wbin[32][72];
    __shared__ float  linv[32];
    __shared__ float  ebuf[32];
    __shared__ float  pl[4][32], pe0[4][32], pe1[4][32];
    __shared__ uint64_t mlds[10];

    const int t    = threadIdx.x;
    const int lane = t & 63, w = t >> 6;            // 8 waves
    const int rh = w & 1, th = w >> 1;              // row-half, tile-quarter
    const int swz  = ((blockIdx.x & 7) * 320) + (blockIdx.x >> 3);  // XCD-contig
    const int qt = swz % 20, bh = swz / 20;
    const int b = bh >> 4, h = bh & 15;
    const int qbase = qt * 32;
    const bool qstm = (qt >= 16);
    const size_t bhoff = (size_t)bh * (SS * HD);
    const int wq = rh * 16, lg = lane >> 4, lc = lane & 15;
    const int RR = qstm ? 16 : 32;
    const int NV = qstm ? 33 : 65;
    const float* tabk = qstm ? smk : relk;

    // zero wbin cooperatively (u32 granularity, all 512 threads)
    {
        uint32_t* wb32 = reinterpret_cast<uint32_t*>(&wbin[0][0]);
        for (int i = t; i < 32 * 36; i += 512) wb32[i] = 0u;
    }

    // mask words: bit j of mlds[kt] covers key kt*64+j
    if (t < 10) {
        uint64_t m = 0;
        const int kb0 = t * 64;
#pragma unroll
        for (int j = 0; j < 64; ++j) {
            int kg = kb0 + j;
            uint8_t mb = (kg < STOK) ? mtok[b * STOK + kg] : mstm[b * STMN + kg - STOK];
            m |= ((uint64_t)(mb ? 1u : 0u)) << j;
        }
        mlds[t] = m;
    }

    // Q fragments (row = qbase+wq+lc): B-operand in swapped QK^T
    const int qrow = qbase + wq + lc;
    v8s aq0 = *reinterpret_cast<const v8s*>(&qb[bhoff + (size_t)qrow * HD + lg * 8]);
    v8s aq1 = *reinterpret_cast<const v8s*>(&qb[bhoff + (size_t)qrow * HD + 32 + lg * 8]);

    // qrel build split 8 ways: wave w handles (rh = w&1, dt = w>>1)
    {
        const int ndt = qstm ? 2 : 4;
        const int dtq = w >> 1;
        if (dtq < ndt) {
            const float* rp = tabk + (size_t)(dtq * 16 + lc) * HD;
            v8s bk0, bk1;
#pragma unroll
            for (int j = 0; j < 8; ++j) {
                bk0[j] = (short)f2b(rp[lg * 8 + j]);
                bk1[j] = (short)f2b(rp[32 + lg * 8 + j]);
            }
            v4f c4 = {0.f, 0.f, 0.f, 0.f};
            c4 = __builtin_amdgcn_mfma_f32_16x16x32_bf16(aq0, bk0, c4, 0, 0, 0);
            c4 = __builtin_amdgcn_mfma_f32_16x16x32_bf16(aq1, bk1, c4, 0, 0, 0);
#pragma unroll
            for (int r = 0; r < 4; ++r)
                qrel[wq + lg * 4 + r][dtq * 16 + lc] = f2b(c4[r]);
        }
        if (w < 2) {    // last column v = NV-1, scalar partial + shfl
            const float* rp = tabk + (size_t)(NV - 1) * HD;
            float part = 0.f;
#pragma unroll
            for (int j = 0; j < 8; ++j) {
                part += b2f((ushort)aq0[j]) * rp[lg * 8 + j];
                part += b2f((ushort)aq1[j]) * rp[32 + lg * 8 + j];
            }
            part += __shfl_xor(part, 16);
            part += __shfl_xor(part, 32);
            if (lg == 0) qrel[wq + lc][NV - 1] = f2b(part);
        }
    }
    __syncthreads();

    // per-lane scalars for this lane's single q-row
    const int gq = qbase + wq + lc;
    const float relLs = b2f(qrel[wq + lc][0]);
    const float relRs = b2f(qrel[wq + lc][2 * RR]);

    const int tile0 = qstm ? 8 : 0;
    const int ntiles = 10 - tile0;
    const int tstart = tile0 + (ntiles * th) / 4;
    const int tend   = tile0 + (ntiles * (th + 1)) / 4;

    float lsum1 = 0.f, e0 = 0.f, e1 = 0.f;
    v4f o[4];
#pragma unroll
    for (int dt = 0; dt < 4; ++dt) o[dt] = (v4f){0.f, 0.f, 0.f, 0.f};
    float* arow = attn_out + ((size_t)bh * SS + qbase) * SS;

    // ---- fused sweep over this wave's tile-quarter ----
    for (int kt = tstart; kt < tend; ++kt) {
        const ushort* kbase = kb + bhoff + (size_t)(kt * 64) * HD;
        const bool dorel = qstm || (kt < 8);
        const uint64_t mw = mlds[kt];
#pragma unroll
        for (int sub = 0; sub < 4; ++sub) {
            v8s bk0 = *reinterpret_cast<const v8s*>(&kbase[(sub * 16 + lc) * HD + lg * 8]);
            v8s bk1 = *reinterpret_cast<const v8s*>(&kbase[(sub * 16 + lc) * HD + 32 + lg * 8]);
            // SWAPPED: A = K-frag, B = Q-frag -> C[row=key][col=q]
            v4f c4 = {0.f, 0.f, 0.f, 0.f};
            c4 = __builtin_amdgcn_mfma_f32_16x16x32_bf16(bk0, aq0, c4, 0, 0, 0);
            c4 = __builtin_amdgcn_mfma_f32_16x16x32_bf16(bk1, aq1, c4, 0, 0, 0);
            const int kgb = kt * 64 + sub * 16 + lg * 4;   // lane's 4 consecutive keys
            float p4[4];
#pragma unroll
            for (int r = 0; r < 4; ++r) {
                int kg = kgb + r;
                int dlt = kg - gq;
                bool inband = dorel && (dlt > -RR) && (dlt < RR);
                float val = c4[r];
                if (dorel) {
                    float rv;
                    if (inband) rv = b2f(qrel[wq + lc][dlt + RR]);
                    else        rv = (dlt <= -RR) ? relLs : relRs;
                    val += rv;
                }
                if ((mw >> (sub * 16 + lg * 4 + r)) & 1) val = NEGINF;
                float p = __expf(val);              // UNNORMALIZED
                lsum1 += p;
                p4[r] = p;
                if (inband) wbin[wq + lc][dlt + RR] = f2b(p);
                else if (dorel) {
                    if (dlt <= -RR) e0 += p;
                    else            e1 += p;
                }
            }
            uint32_t lo = (uint32_t)f2b(p4[0]) | ((uint32_t)f2b(p4[1]) << 16);
            uint32_t hi = (uint32_t)f2b(p4[2]) | ((uint32_t)f2b(p4[3]) << 16);
            uint64_t pk64 = (uint64_t)lo | ((uint64_t)hi << 32);
            *reinterpret_cast<uint64_t*>(&Pfull[wq + lc][kgb]) = pk64;
        }
        // PV for this tile (A from own rows' Pfull, B = V^T frags)
        v8s ap0 = *reinterpret_cast<const v8s*>(&Pfull[wq + lc][kt * 64 + lg * 8]);
        v8s ap1 = *reinterpret_cast<const v8s*>(&Pfull[wq + lc][kt * 64 + 32 + lg * 8]);
        const ushort* vbase = vtb + bhoff + kt * 64;
#pragma unroll
        for (int dt = 0; dt < 4; ++dt) {
            v8s bv0 = *reinterpret_cast<const v8s*>(&vbase[(size_t)(dt * 16 + lc) * SS + lg * 8]);
            v8s bv1 = *reinterpret_cast<const v8s*>(&vbase[(size_t)(dt * 16 + lc) * SS + 32 + lg * 8]);
            o[dt] = __builtin_amdgcn_mfma_f32_16x16x32_bf16(ap0, bv0, o[dt], 0, 0, 0);
            o[dt] = __builtin_amdgcn_mfma_f32_16x16x32_bf16(ap1, bv1, o[dt], 0, 0, 0);
        }
    }

    // per-lane reduces over lg groups -> per-row partials for (rh, th)
    {
        float s = lsum1;
        s += __shfl_xor(s, 16); s += __shfl_xor(s, 32);
        float e0s = e0;
        e0s += __shfl_xor(e0s, 16); e0s += __shfl_xor(e0s, 32);
        float e1s = e1;
        e1s += __shfl_xor(e1s, 16); e1s += __shfl_xor(e1s, 32);
        if (lg == 0) {
            pl[th][wq + lc]  = s;
            pe0[th][wq + lc] = e0s;
            pe1[th][wq + lc] = e1s;
        }
    }
    __syncthreads();

    // combine quarters (one thread per row)
    if (t < 32) {
        int row = t;
        float ls  = pl[0][row] + pl[1][row] + pl[2][row] + pl[3][row];
        linv[row] = 1.f / ls;
        float e0s = pe0[0][row] + pe0[1][row] + pe0[2][row] + pe0[3][row];
        float e1s = pe1[0][row] + pe1[1][row] + pe1[2][row] + pe1[3][row];
        ebuf[row] = e1s;
        wbin[row][0] = f2b(e0s);
        if (qstm) wbin[row][32] = f2b(e1s);
    }
    __syncthreads();

    // ---- row-contiguous normalize+write of attn (nt stores); 4 rows/wave ----
    {
        int row = w * 4 + lg;
        float iv = linv[row];
        float* rowp = arow + (size_t)row * SS;
        if (qstm) {
            v4f z = (v4f){0.f, 0.f, 0.f, 0.f};
#pragma unroll
            for (int kt = 0; kt < 8; ++kt)
                __builtin_nontemporal_store(z,
                    reinterpret_cast<v4f*>(&rowp[kt * 64 + lc * 4]));
#pragma unroll
            for (int kt = 8; kt < 10; ++kt) {
                ushort4 pk = *reinterpret_cast<ushort4*>(&Pfull[row][kt * 64 + lc * 4]);
                v4f pv4;
                pv4[0] = b2f(pk.x) * iv;
                pv4[1] = b2f(pk.y) * iv;
                pv4[2] = b2f(pk.z) * iv;
                pv4[3] = b2f(pk.w) * iv;
                __builtin_nontemporal_store(pv4,
                    reinterpret_cast<v4f*>(&rowp[kt * 64 + lc * 4]));
            }
        } else {
#pragma unroll
            for (int kt = 0; kt < 10; ++kt) {
                ushort4 pk = *reinterpret_cast<ushort4*>(&Pfull[row][kt * 64 + lc * 4]);
                v4f pv4;
                pv4[0] = b2f(pk.x) * iv;
                pv4[1] = b2f(pk.y) * iv;
                pv4[2] = b2f(pk.z) * iv;
                pv4[3] = b2f(pk.w) * iv;
                __builtin_nontemporal_store(pv4,
                    reinterpret_cast<v4f*>(&rowp[kt * 64 + lc * 4]));
            }
        }
    }
    __syncthreads();

    // ---- overlay write (ALL waves) + rel-v staging ----
    // Pfull dead region layout (ushort idx): Rv 0..4607 (stride 72),
    // overlays (f32) at ushort idx 4608 + q*4096.
    {
        float* ob = reinterpret_cast<float*>(&Pfull[0][0] + 4608) + th * 2048;
#pragma unroll
        for (int dt = 0; dt < 4; ++dt)
#pragma unroll
            for (int r = 0; r < 4; ++r)
                ob[(wq + lg * 4 + r) * 64 + dt * 16 + lc] = o[dt][r];
    }
    {
        ushort* Rv = &Pfull[0][0];
        const float* tabv = qstm ? smv : relv;
        for (int idx = t; idx < 64 * 64; idx += 512) {
            int d = idx >> 6, v = idx & 63;
            float f = (v < NV) ? tabv[(size_t)v * HD + d] : 0.f;
            Rv[d * 72 + v] = f2b(f);
        }
    }
    __syncthreads();

    // ---- final phase split by dt: wave (rh, th) handles dt = th ----
    {
        const int dtw = th;
        const float* obase = reinterpret_cast<const float*>(&Pfull[0][0] + 4608);
        v4f of = (v4f){0.f, 0.f, 0.f, 0.f};
#pragma unroll
        for (int q = 0; q < 4; ++q) {
            const float* ob = obase + q * 2048;
#pragma unroll
            for (int r = 0; r < 4; ++r)
                of[r] += ob[(wq + lg * 4 + r) * 64 + dtw * 16 + lc];
        }
        const ushort* Rv = &Pfull[0][0];
        v8s aw0 = *reinterpret_cast<const v8s*>(&wbin[wq + lc][lg * 8]);
        v8s aw1 = *reinterpret_cast<const v8s*>(&wbin[wq + lc][32 + lg * 8]);
        v8s bv0 = *reinterpret_cast<const v8s*>(&Rv[(dtw * 16 + lc) * 72 + lg * 8]);
        v8s bv1 = *reinterpret_cast<const v8s*>(&Rv[(dtw * 16 + lc) * 72 + 32 + lg * 8]);
        of = __builtin_amdgcn_mfma_f32_16x16x32_bf16(aw0, bv0, of, 0, 0, 0);
        of = __builtin_amdgcn_mfma_f32_16x16x32_bf16(aw1, bv1, of, 0, 0, 0);
        if (!qstm) {   // rank-1 fixup for bin v=64
#pragma unroll
            for (int r = 0; r < 4; ++r)
                of[r] += ebuf[wq + lg * 4 + r] * relv[(size_t)64 * HD + dtw * 16 + lc];
        }
        // normalize and write ctx as bf16 hi/lo [b][s][h*64+d]
#pragma unroll
        for (int r = 0; r < 4; ++r) {
            int gq2 = qbase + wq + lg * 4 + r;
            size_t idx = ((size_t)b * SS + gq2) * DIM + h * HD + dtw * 16 + lc;
            float v = of[r] * linv[wq + lg * 4 + r];
            ushort hi = f2b(v);
            ctxh[idx] = hi;
            ctxl[idx] = f2b(v - b2f(hi));
        }
    }
}

// ---------------------------------------------------------------------------
extern "C" void kernel_launch(void* const* d_in, const int* in_sizes, int n_in,
                              void* d_out, int out_size, void* d_ws, size_t ws_size,
                              hipStream_t stream)
{
    const float*   stok  = (const float*)d_in[0];
    const float*   stm   = (const float*)d_in[1];
    const uint8_t* mtok  = (const uint8_t*)d_in[2];
    const uint8_t* mstm  = (const uint8_t*)d_in[3];
    const float*   qkv_w = (const float*)d_in[4];
    const float*   qkv_b = (const float*)d_in[5];
    const float*   out_w = (const float*)d_in[6];
    const float*   out_b = (const float*)d_in[7];
    const float*   relk  = (const float*)d_in[8];
    const float*   relv  = (const float*)d_in[9];
    const float*   smk   = (const float*)d_in[10];
    const float*   smv   = (const float*)d_in[11];

    float* out_final = (float*)d_out;
    float* out_attn  = out_final + (size_t)BB * SS * DIM;

    const size_t SZ = (size_t)BB * HH * SS * HD;           // 5,242,880
    ushort* qb16 = (ushort*)d_ws;
    ushort* kb16 = qb16 + SZ;
    ushort* vt16 = kb16 + SZ;
    ushort* xb16 = vt16 + SZ;                              // 5,242,880 ushorts
    ushort* wb16 = xb16 + SZ;                              // 3,145,728 ushorts
    ushort* ctxh = wb16 + (size_t)3 * DIM * DIM;
    ushort* ctxl = ctxh + SZ;
    ushort* woh  = ctxl + SZ;                              // 1,048,576 ushorts
    ushort* wol  = woh + (size_t)DIM * DIM;

    cvt_bf16<<<dim3(9216), dim3(256), 0, stream>>>(stok, stm, qkv_w, out_w,
                                                   xb16, wb16, woh, wol);
    gemm_qkv_mfma<<<dim3(960), dim3(256), 0, stream>>>(xb16, wb16, qkv_b, qb16, kb16, vt16);
    attn_mfma<<<dim3(2560), dim3(512), 0, stream>>>(qb16, kb16, vt16, mtok, mstm,
                                                    relk, relv, smk, smv, out_attn, ctxh, ctxl);
    gemm_out_mfma<<<dim3(640), dim3(256), 0, stream>>>(ctxh, ctxl, woh, wol, out_b, out_final);
}